// Round 1
// baseline (1609.543 us; speedup 1.0000x reference)
//
#include <hip/hip_runtime.h>

#define CC 256      // checks (rows of H)
#define VV 512      // variables (cols of H)
#define MAXRD 26    // row-degree cap (mean 6, Binomial(512, 6/512))
#define MAXCD 18    // col-degree cap (mean 3)

__global__ __launch_bounds__(512)
void ldpc_bp_kernel(const float* __restrict__ llr_g,
                    const int*   __restrict__ H_g,
                    const int*   __restrict__ it_g,
                    int*         __restrict__ out_g,
                    float*       __restrict__ ws)
{
    // transposed [slot][c] layouts -> lane-consecutive, bank-conflict-free
    __shared__ float          llr_s[VV];            //  2 KB
    __shared__ unsigned short rlistT[MAXRD][CC];    // 13 KB  row supports (sorted v)
    __shared__ float          tcacheT[MAXRD][CC];   // 26 KB  tanh(0.5*m_vtoc) at nnz
    __shared__ unsigned short rdeg_s[CC];
    __shared__ unsigned short clistT[MAXCD][VV];    // 18 KB  col supports (sorted c)
    __shared__ unsigned short cdeg_s[VV];
    __shared__ float          colbuf[CC];
    __shared__ float          bcast_vnew;

    const int tid = threadIdx.x;
    float* mv = ws;                                 // m_vtoc [VV][CC]
    float* mc = ws + (size_t)VV * CC;               // m_ctov [CC][VV]

    // ---- setup ----
    llr_s[tid] = llr_g[tid];
    for (int k = tid; k < CC * VV; k += 512) mc[k] = 0.0f;   // m_ctov = zeros

    {   // column lists: coalesced over j per c
        int d = 0;
        for (int c = 0; c < CC; ++c) {
            if (H_g[c * VV + tid] != 0) {
                if (d < MAXCD) clistT[d][tid] = (unsigned short)c;
                ++d;
            }
        }
        cdeg_s[tid] = (unsigned short)(d < MAXCD ? d : MAXCD);
    }
    if (tid < CC) {   // row lists + tanh cache init (m_vtoc = ones)
        int d = 0;
        const int* hrow = H_g + tid * VV;
        for (int v = 0; v < VV; ++v) {
            if (hrow[v] != 0) {
                if (d < MAXRD) {
                    rlistT[d][tid]  = (unsigned short)v;
                    tcacheT[d][tid] = tanhf(0.5f * 1.0f);
                }
                ++d;
            }
        }
        rdeg_s[tid] = (unsigned short)(d < MAXRD ? d : MAXRD);
    }
    __syncthreads();

    const int max_iter = it_g[0];

    for (int it = 0; it < max_iter; ++it) {
        // ---- p1: v->c sweep. Per-column state is thread-private: no barriers.
        if (tid < CC) {
            const int c   = tid;
            const int deg = rdeg_s[c];
            int kptr  = 0;
            int nextv = (deg > 0) ? (int)rlistT[0][c] : VV;
            for (int i = 0; i < VV; ++i) {
                float prod = 1.0f;                       // ascending-v sequential product
                for (int k = 0; k < deg; ++k) prod *= tcacheT[k][c];
                float l  = llr_s[i];
                float sg = (l > 0.0f) ? 1.0f : ((l < 0.0f) ? -1.0f : 0.0f);
                float newv = sg * prod;
                mv[i * CC + c] = newv;                   // dense row write (coalesced)
                if (i == nextv) {                        // row i in this column's support
                    tcacheT[kptr][c] = tanhf(0.5f * newv);
                    ++kptr;
                    nextv = (kptr < deg) ? (int)rlistT[kptr][c] : VV;
                }
            }
        }
        __threadfence_block();
        __syncthreads();

        // ---- p2: c->v sweep, sequential over i with barriers
        for (int i = 0; i < CC; ++i) {
            if (tid < CC) colbuf[tid] = mc[tid * VV + i];   // col = m_ctov[:, i].copy()
            __syncthreads();

            const int j = tid;
            float s = 0.0f;                                  // ascending-c sequential dot
            const int d = cdeg_s[j];
            for (int k = 0; k < d; ++k) s += colbuf[clistT[k][j]];
            float base = s - mv[j * CC + i];
            if (j == i) bcast_vnew = 2.0f * atanf(expf(0.5f * base));
            __syncthreads();

            float arg = base;
            if (j > i) {                                     // adj only for jidx > i
                const int di = rdeg_s[i];
                bool hit = false;
                for (int k = 0; k < di; ++k) hit |= ((int)rlistT[k][i] == j);
                if (hit) arg = base + (bcast_vnew - colbuf[i]);
            }
            float val = 2.0f * atanf(expf(0.5f * arg));
            mc[i * VV + j] = val;                            // m_ctov[i, :] = phi(base+adj)
            __threadfence_block();
            __syncthreads();
        }
    }

    // ---- final hard decision, v = 0..3 only; strict sequential f32 product
    if (tid < 4) {
        float prod = 1.0f;
        for (int c = 0; c < CC; ++c) prod *= tanhf(0.5f * mc[c * VV + tid]);
        float l  = llr_s[tid];
        float sg = (l > 0.0f) ? 1.0f : ((l < 0.0f) ? -1.0f : 0.0f);
        float soft = sg * prod;
        out_g[tid] = (soft > 0.0f) ? 1 : 0;
    }
}

extern "C" void kernel_launch(void* const* d_in, const int* in_sizes, int n_in,
                              void* d_out, int out_size, void* d_ws, size_t ws_size,
                              hipStream_t stream) {
    const float* llr = (const float*)d_in[0];
    const int*   H   = (const int*)d_in[1];
    const int*   mi  = (const int*)d_in[2];
    int*         out = (int*)d_out;
    float*       ws  = (float*)d_ws;
    hipLaunchKernelGGL(ldpc_bp_kernel, dim3(1), dim3(512), 0, stream,
                       llr, H, mi, out, ws);
}

// Round 2
// 1152.763 us; speedup vs baseline: 1.3962x; 1.3962x over previous
//
#include <hip/hip_runtime.h>

#define CC 256      // checks
#define VV 512      // variables
#define MAXRD 26    // row-degree cap (proven sufficient: round-0 passed absmax 0)
#define MAXCD 18    // col-degree cap (proven sufficient)
#define PSTRIDE 29  // deg+1 states padded (29 coprime with 32 banks)

__global__ __launch_bounds__(256)
void ldpc_bp2(const float* __restrict__ llr_g, const int* __restrict__ H_g,
              const int* __restrict__ it_g, int* __restrict__ out_g,
              float* __restrict__ ws)
{
    __shared__ float          llr_s[VV];             //  2 KB
    __shared__ unsigned short rlistT[MAXRD][CC];     // 13 KB  row supports (sorted v)
    __shared__ unsigned short rdeg_s[CC];
    __shared__ float          Pst[CC][PSTRIDE];      // 29 KB  P_c(k) prefix states
    __shared__ unsigned short clistT[MAXCD][CC];     //  9 KB  col supports, cols<256
    __shared__ unsigned short cdeg_s[CC];
    __shared__ float          colbuf[CC];            //  1 KB  staged m_ctov[:,s]
    __shared__ float          fwd_s[2];              //  lag-1 cell forward
    __shared__ float          tb[CC][5];             //  5 KB  final tanh buffer (padded)

    const int tid = threadIdx.x;
    float* __restrict__ mcT = ws;                    // [CC][CC]: mcT[a][b] = m_ctov[b][a]

    // ---- setup ----
    llr_s[tid]      = llr_g[tid];
    llr_s[tid + CC] = llr_g[tid + CC];
    {   // zero live m_ctov block (must re-zero every launch: no re-poison between replays)
        float4 z; z.x = z.y = z.z = z.w = 0.0f;
        float4* m4 = (float4*)mcT;
        for (int k = tid; k < CC * CC / 4; k += CC) m4[k] = z;
    }
    {   // row lists: thread = check c, vectorized row scan (lines L2-cached for col scan)
        int d = 0;
        const int4* hrow = (const int4*)(H_g + tid * VV);
        for (int g = 0; g < VV / 4; ++g) {
            int4 h = hrow[g];
            const int v = g * 4;
            if (h.x) { if (d < MAXRD) rlistT[d][tid] = (unsigned short)(v);     ++d; }
            if (h.y) { if (d < MAXRD) rlistT[d][tid] = (unsigned short)(v + 1); ++d; }
            if (h.z) { if (d < MAXRD) rlistT[d][tid] = (unsigned short)(v + 2); ++d; }
            if (h.w) { if (d < MAXRD) rlistT[d][tid] = (unsigned short)(v + 3); ++d; }
        }
        rdeg_s[tid] = (unsigned short)(d < MAXRD ? d : MAXRD);
    }
    {   // col lists for columns < 256 only (cols >= 256 of m_ctov are never read)
        int d = 0;
        for (int c = 0; c < CC; ++c) {
            if (H_g[c * VV + tid] != 0) {
                if (d < MAXCD) clistT[d][tid] = (unsigned short)c;
                ++d;
            }
        }
        cdeg_s[tid] = (unsigned short)(d < MAXCD ? d : MAXCD);
    }
    __syncthreads();

    const int   max_iter = it_g[0];
    const float T05      = tanhf(0.5f);

    for (int pass = 0; pass < max_iter; ++pass) {
        // ---- p1: per-check prefix-state computation (thread = check c) ----
        // P_c(k) = left-assoc product over support of tanh factors, first k updated.
        // Old factors recomputed bit-exactly from previous pass's Pst (same ops).
        {
            const int c   = tid;
            const int deg = rdeg_s[c];
            float NP = 1.0f;                       // running left-assoc prefix of new t'
            for (int k = 0; k <= deg; ++k) {
                float P = NP;
                for (int idx = k; idx < deg; ++idx) {   // old tail, ascending v
                    float told;
                    if (pass == 0) {
                        told = T05;                      // tanh(0.5*1.0)
                    } else {
                        const int   v  = rlistT[idx][c];
                        const float l  = llr_s[v];
                        const float sg = (l > 0.f) ? 1.f : ((l < 0.f) ? -1.f : 0.f);
                        told = tanhf(0.5f * (sg * Pst[c][idx]));  // == prev pass t'
                    }
                    P *= told;
                }
                Pst[c][k] = P;                     // writes trail reads (idx >= k old)
                if (k < deg) {                     // t'_k from newv_k = sg_k * P_c(k)
                    const int   v  = rlistT[k][c];
                    const float l  = llr_s[v];
                    const float sg = (l > 0.f) ? 1.f : ((l < 0.f) ? -1.f : 0.f);
                    NP *= tanhf(0.5f * (sg * P));
                }
            }
        }
        __syncthreads();

        // ---- p2: 256 sequential steps, 2 barriers each, deferred column store ----
        float prevval = 0.0f;
        for (int s = 0; s < CC; ++s) {
            // deferred store of previous step's value: cell (tid, s-1).
            // Issued a full step before any reader needs it -> drain is free.
            if (s > 0) mcT[tid * CC + (s - 1)] = prevval;

            // stage m_ctov[:, s] = row s of mcT (coalesced 1 KB). Cell (s, s-1) is
            // concurrently being stored by thread s -> take it from LDS forward.
            float cl = mcT[(size_t)s * CC + tid];
            if (s > 0 && tid == s - 1) cl = fwd_s[(s - 1) & 1];
            colbuf[tid] = cl;
            __syncthreads();                       // barrier A (also drains the store)

            // k_j = #{v in supp(check s) : v < tid}, hit = H[s,tid]==1
            const int di = rdeg_s[s];
            int  kj  = 0;
            bool hit = false;
            for (int k = 0; k < di; ++k) {
                const int rv = rlistT[k][s];       // uniform -> LDS broadcast
                kj  += (rv < tid) ? 1 : 0;
                hit |= (rv == tid);
            }
            // base[j] = sum_{c in suppcol(j)} colbuf[c]  -  mv[j,s]
            const int cd = cdeg_s[tid];
            float base = 0.0f;
            for (int k = 0; k < cd; ++k) base += colbuf[clistT[k][tid]];
            const float lj  = llr_s[tid];
            const float sgj = (lj > 0.f) ? 1.f : ((lj < 0.f) ? -1.f : 0.f);
            base -= sgj * Pst[s][kj];

            // v_new = phi(base[s]) — recomputed redundantly (bit-identical) by all
            const int cdi = cdeg_s[s];
            float bi = 0.0f;
            for (int k = 0; k < cdi; ++k) bi += colbuf[clistT[k][s]];
            int ki = 0;
            for (int k = 0; k < di; ++k) ki += ((int)rlistT[k][s] < s) ? 1 : 0;
            const float ls  = llr_s[s];
            const float sgs = (ls > 0.f) ? 1.f : ((ls < 0.f) ? -1.f : 0.f);
            bi -= sgs * Pst[s][ki];
            const float vnew = 2.0f * atanf(expf(0.5f * bi));

            const float arg = (hit && (tid > s)) ? (base + (vnew - colbuf[s])) : base;
            const float val = 2.0f * atanf(expf(0.5f * arg));

            if (tid == s + 1) fwd_s[s & 1] = val;  // lag-1 cell (s+1, s) for next step
            prevval = val;
            __syncthreads();                       // barrier B
        }
        mcT[tid * CC + (CC - 1)] = prevval;        // flush column 255
        __syncthreads();
    }

    // ---- final hard decision: parallel tanh, then strict sequential product ----
    {
        for (int v = 0; v < 4; ++v)
            tb[tid][v] = tanhf(0.5f * mcT[v * CC + tid]);   // coalesced per v
    }
    __syncthreads();
    if (tid < 4) {
        float p = 1.0f;
        for (int c = 0; c < CC; ++c) p *= tb[c][tid];       // ascending c, left-assoc
        const float l  = llr_s[tid];
        const float sg = (l > 0.f) ? 1.f : ((l < 0.f) ? -1.f : 0.f);
        const float soft = sg * p;
        out_g[tid] = (soft > 0.0f) ? 1 : 0;
    }
}

extern "C" void kernel_launch(void* const* d_in, const int* in_sizes, int n_in,
                              void* d_out, int out_size, void* d_ws, size_t ws_size,
                              hipStream_t stream) {
    const float* llr = (const float*)d_in[0];
    const int*   H   = (const int*)d_in[1];
    const int*   mi  = (const int*)d_in[2];
    int*         out = (int*)d_out;
    float*       ws  = (float*)d_ws;
    hipLaunchKernelGGL(ldpc_bp2, dim3(1), dim3(256), 0, stream,
                       llr, H, mi, out, ws);
}